// Round 6
// baseline (715.862 us; speedup 1.0000x reference)
//
#include <hip/hip_runtime.h>
#include <hip/hip_bf16.h>

#define N_NODES 200000
#define E1 1600000
#define N1P 100000
#define E2P 100000
#define N2P 50000
#define BGR 1000
#define C1 32
#define C2 64
#define HIDN 25
#define NCLS 10
#define SCAN_CHUNK 196   // 1024*196 = 200704 >= N_NODES

typedef short short8 __attribute__((ext_vector_type(8)));
typedef int int4v __attribute__((ext_vector_type(4)));
typedef float f32x4 __attribute__((ext_vector_type(4)));
typedef float f32x2 __attribute__((ext_vector_type(2)));

union FragU { int4v i; short8 s; };

__device__ __forceinline__ float elu1(float v) {
    return v > 0.f ? v : expm1f(v);
}
__device__ __forceinline__ float bf2f(unsigned short u) {
    return __uint_as_float(((unsigned int)u) << 16);
}
__device__ __forceinline__ unsigned int pk_bf16(float a, float b) {
    unsigned int r;
    asm("v_cvt_pk_bf16_f32 %0, %1, %2" : "=v"(r) : "v"(a), "v"(b));
    return r;
}
__device__ __forceinline__ void atomic_pk_bf16(unsigned short* p, unsigned int pk) {
    asm volatile("global_atomic_pk_add_bf16 %0, %1, off" :: "v"(p), "v"(pk) : "memory");
}

// ---------------- counting sort step 1: histogram of dst
__global__ __launch_bounds__(256) void hist_kernel(
    const int* __restrict__ ei, int* __restrict__ cnt)
{
    int e = blockIdx.x * 256 + threadIdx.x;
    if (e < E1) atomicAdd(&cnt[ei[E1 + e]], 1);
}

// ---------------- counting sort step 2: exclusive scan (single block)
__global__ __launch_bounds__(1024) void scan_kernel(
    const int* __restrict__ cnt, int* __restrict__ offs)
{
    __shared__ int ssum[1024];
    int t = threadIdx.x;
    int base = t * SCAN_CHUNK;
    int s = 0;
    for (int i = 0; i < SCAN_CHUNK; ++i) {
        int idx = base + i;
        s += (idx < N_NODES) ? cnt[idx] : 0;
    }
    ssum[t] = s;
    __syncthreads();
    for (int off = 1; off < 1024; off <<= 1) {
        int v = (t >= off) ? ssum[t - off] : 0;
        __syncthreads();
        ssum[t] += v;
        __syncthreads();
    }
    int run = (t == 0) ? 0 : ssum[t - 1];
    for (int i = 0; i < SCAN_CHUNK; ++i) {
        int idx = base + i;
        if (idx < N_NODES) { offs[idx] = run; run += cnt[idx]; }
    }
}

// ---------------- counting sort step 3: scatter edge ids into dst order
__global__ __launch_bounds__(256) void scatter_kernel(
    const int* __restrict__ ei, const int* __restrict__ offs,
    int* __restrict__ cur, int* __restrict__ sorted_eid, int* __restrict__ sorted_dst)
{
    int e = blockIdx.x * 256 + threadIdx.x;
    if (e >= E1) return;
    int d = ei[E1 + e];
    int r = atomicAdd(&cur[d], 1);
    int slot = offs[d] + r;
    sorted_eid[slot] = e;
    sorted_dst[slot] = d;
}

// ---------------- build conv1 B [32][32] as MFMA B-fragments with EVEN/ODD column perm
__global__ __launch_bounds__(256) void bgbuild1_kernel(
    const float* __restrict__ w2, const float* __restrict__ b2,
    unsigned int* __restrict__ W2f)
{
    int q = blockIdx.x * 256 + threadIdx.x;     // 512 u32 total
    if (q >= 512) return;
    int jj = q & 3, l = (q >> 2) & 63, m = q >> 8;
    int k0 = (l >> 4) * 8 + 2 * jj;
    int o = 2 * (l & 15) + m;                   // even/odd channel perm
    float v0 = (k0 < 25) ? w2[k0 * 32 + o] : (k0 == 25 ? b2[o] : 0.f);
    int k1 = k0 + 1;
    float v1 = (k1 < 25) ? w2[k1 * 32 + o] : (k1 == 25 ? b2[o] : 0.f);
    W2f[q] = pk_bf16(v0, v1);
}

// ---------------- conv1: MFMA messages for 256 dst-sorted edges + in-LDS segmented
// reduction over dst runs; interior runs -> plain stores, boundary runs -> pk atomics
__global__ __launch_bounds__(256) void conv1_kernel(
    const float* __restrict__ x, const float* __restrict__ ea,
    const int* __restrict__ ei,
    const float* __restrict__ w1, const float* __restrict__ b1,
    const unsigned int* __restrict__ W2f,
    const int* __restrict__ sorted_eid, const int* __restrict__ sorted_dst,
    unsigned short* __restrict__ agg1b)
{
    __shared__ unsigned int afrag[16][4][64];   // 16 KB
    __shared__ unsigned int msg_lds[256][17];   // 17 KB (16 ch-pairs + pad)
    __shared__ int dst_lds[258];                // [256]=prev global dst, [257]=next
    __shared__ int runstart[260];
    __shared__ int wave_cnt[4];
    __shared__ int nruns;

    int t = threadIdx.x;
    int base = blockIdx.x * 256;                // E1 % 256 == 0
    int slot = base + t;
    int eid = sorted_eid[slot];
    int d = sorted_dst[slot];
    dst_lds[t] = d;
    if (t == 0) dst_lds[256] = (base > 0) ? sorted_dst[base - 1] : -1;
    if (t == 1) dst_lds[257] = (base + 256 < E1) ? sorted_dst[base + 256] : -1;

    f32x2 a = ((const f32x2*)ea)[eid];
    int s = ei[eid];
    float xv = x[s];

    float v[26];
#pragma unroll
    for (int h = 0; h < HIDN; ++h) {
        float u = fmaf(a.x, w1[h], fmaf(a.y, w1[HIDN + h], b1[h]));
        v[h] = fmaxf(u, 0.f) * xv;
    }
    v[25] = xv;

    int tile = t >> 4, r16 = t & 15;
#pragma unroll
    for (int p = 0; p < 13; ++p) {              // pair p covers k = 2p, 2p+1
        int g = p >> 2, j = p & 3;
        afrag[tile][j][g * 16 + r16] = pk_bf16(v[2 * p], v[2 * p + 1]);
    }
    afrag[tile][1][48 + r16] = 0;               // k = 26..31 zero
    afrag[tile][2][48 + r16] = 0;
    afrag[tile][3][48 + r16] = 0;
    __syncthreads();

    int lane = t & 63, wave = t >> 6;
    FragU bf0, bf1;
    bf0.i = *(const int4v*)(W2f + lane * 4);
    bf1.i = *(const int4v*)(W2f + (64 + lane) * 4);
    int c = lane & 15, rg = lane >> 4;

#pragma unroll
    for (int ti = 0; ti < 4; ++ti) {
        int tl = wave * 4 + ti;
        FragU af;
        af.i.x = afrag[tl][0][lane];
        af.i.y = afrag[tl][1][lane];
        af.i.z = afrag[tl][2][lane];
        af.i.w = afrag[tl][3][lane];
        f32x4 a0 = (f32x4){0.f, 0.f, 0.f, 0.f};
        f32x4 a1 = (f32x4){0.f, 0.f, 0.f, 0.f};
        a0 = __builtin_amdgcn_mfma_f32_16x16x32_bf16(af.s, bf0.s, a0, 0, 0, 0);
        a1 = __builtin_amdgcn_mfma_f32_16x16x32_bf16(af.s, bf1.s, a1, 0, 0, 0);
#pragma unroll
        for (int jj = 0; jj < 4; ++jj)          // lane c holds channels (2c, 2c+1)
            msg_lds[tl * 16 + rg * 4 + jj][c] = pk_bf16(a0[jj], a1[jj]);
    }
    __syncthreads();

    // run detection: t==0 always starts a run
    int prevd = (t == 0) ? -2 : dst_lds[t - 1];
    bool flag = (t == 0) || (d != prevd);
    unsigned long long mask = __ballot(flag);
    int ln = lane;
    if (ln == 0) wave_cnt[wave] = __popcll(mask);
    __syncthreads();
    int wbase = 0;
    for (int i = 0; i < wave; ++i) wbase += wave_cnt[i];
    if (flag)
        runstart[wbase + __popcll(mask & ((1ull << ln) - 1ull))] = t;
    if (t == 0) {
        int R = wave_cnt[0] + wave_cnt[1] + wave_cnt[2] + wave_cnt[3];
        nruns = R;
        runstart[R] = 256;
    }
    __syncthreads();
    int R = nruns;

    // 16 groups x 16 lanes; group g handles runs g, g+16, ...; lane gl = channel pair
    int grp = t >> 4, gl = t & 15;
    for (int r = grp; r < R; r += 16) {
        int st = runstart[r], en = runstart[r + 1];
        int rd = dst_lds[st];
        float s0 = 0.f, s1 = 0.f;
        for (int i = st; i < en; ++i) {
            unsigned int u = msg_lds[i][gl];
            s0 += __uint_as_float(u << 16);
            s1 += __uint_as_float(u & 0xffff0000u);
        }
        bool open = (r == 0 && rd == dst_lds[256]) || (r == R - 1 && rd == dst_lds[257]);
        unsigned short* p = agg1b + (size_t)rd * C1 + 2 * gl;
        if (open) atomic_pk_bf16(p, pk_bf16(s0, s1));
        else      *(unsigned int*)p = pk_bf16(s0, s1);
    }
}

// ---------------- finish conv1 (root+bias+elu) and pool1 (pairwise max) + pos mean
__global__ __launch_bounds__(256) void pool1_kernel(
    const unsigned short* __restrict__ agg1b, const float* __restrict__ x,
    const float* __restrict__ root1, const float* __restrict__ bias1,
    const float* __restrict__ pos, unsigned short* __restrict__ x1b,
    float* __restrict__ pos1)
{
    int t = blockIdx.x * blockDim.x + threadIdx.x;
    if (t >= N1P * C1) return;
    int j = t >> 5, o = t & 31;
    int na = 2 * j, nb = 2 * j + 1;
    float r = root1[o], bo = bias1[o];
    float ha = elu1(bf2f(agg1b[(size_t)na * C1 + o]) + x[na] * r + bo);
    float hb = elu1(bf2f(agg1b[(size_t)nb * C1 + o]) + x[nb] * r + bo);
    float mx = fmaxf(ha, hb);
    x1b[t] = (unsigned short)(pk_bf16(mx, mx) & 0xffffu);
    if (o < 2) pos1[j * 2 + o] = 0.5f * (pos[na * 2 + o] + pos[nb * 2 + o]);
}

// ---------------- global max|cart| over pooled edges
__global__ __launch_bounds__(256) void maxabs_kernel(
    const int* __restrict__ ei2, const float* __restrict__ pos1,
    unsigned int* __restrict__ maxbits)
{
    int e = blockIdx.x * blockDim.x + threadIdx.x;
    float m = 0.f;
    if (e < E2P) {
        int s = ei2[e], d = ei2[E2P + e];
        float c0 = pos1[2 * s] - pos1[2 * d];
        float c1 = pos1[2 * s + 1] - pos1[2 * d + 1];
        m = fmaxf(fabsf(c0), fabsf(c1));
    }
#pragma unroll
    for (int off = 32; off; off >>= 1)
        m = fmaxf(m, __shfl_down(m, off));
    if ((threadIdx.x & 63) == 0)
        atomicMax(maxbits, __float_as_uint(m));
}

// ---------------- build conv2 B [832][64] fragments; column perm for pk epilogue
__global__ __launch_bounds__(256) void bgbuild_kernel(
    const float* __restrict__ w2, const float* __restrict__ b2,
    unsigned int* __restrict__ Bg)
{
    int idx = blockIdx.x * 256 + threadIdx.x;           // pair index, 26624 total
    if (idx >= 26 * 4 * 64 * 4) return;
    int g0 = idx * 2;
    int j = g0 & 7;
    int l = (g0 >> 3) & 63;
    int nb = (g0 >> 9) & 3;
    int kt = g0 >> 11;
    int k = kt * 32 + (l >> 4) * 8 + j;
    int o = (nb >> 1) * 32 + 2 * (l & 15) + (nb & 1);   // perm
    float v0, v1;
    if (k < 800) { v0 = w2[k * 64 + o]; v1 = w2[(k + 1) * 64 + o]; }
    else         { v0 = b2[(k - 800) * 64 + o]; v1 = b2[(k - 799) * 64 + o]; }
    Bg[idx] = pk_bf16(v0, v1);
}

// ---------------- conv2 via MFMA: 256 edges/block, kt-outer, pk-bf16 atomic epilogue
__global__ __launch_bounds__(256) void conv2_kernel(
    const int* __restrict__ ei2, const float* __restrict__ pos1,
    const unsigned short* __restrict__ x1b,
    const float* __restrict__ w1, const float* __restrict__ b1,
    const unsigned int* __restrict__ maxbits,
    const unsigned int* __restrict__ Bg,
    unsigned short* __restrict__ agg2b)
{
    __shared__ __align__(16) unsigned short xs_lds[256][40];  // 20 KB
    __shared__ float hid_lds[256][27];                         // 27.6 KB
    __shared__ int dst_lds[256];

    int t = threadIdx.x;
    int ge = blockIdx.x * 256 + t;

    {   // phase 1: per-edge hid + xs staging (x1 already bf16)
        float inv = 0.5f / __uint_as_float(maxbits[0]);
        int s = 0, d = 0;
        if (ge < E2P) { s = ei2[ge]; d = ei2[E2P + ge]; }
        dst_lds[t] = d;
        float a0 = (pos1[2 * s] - pos1[2 * d]) * inv + 0.5f;
        float a1 = (pos1[2 * s + 1] - pos1[2 * d + 1]) * inv + 0.5f;
#pragma unroll
        for (int h = 0; h < HIDN; ++h) {
            float u = fmaf(a0, w1[h], fmaf(a1, w1[HIDN + h], b1[h]));
            hid_lds[t][h] = fmaxf(u, 0.f);
        }
        const int4v* xp = (const int4v*)(x1b + (size_t)s * C1);
#pragma unroll
        for (int q = 0; q < 4; ++q)
            *(int4v*)&xs_lds[t][q * 8] = xp[q];
    }
    __syncthreads();

    int lane = t & 63, wave = t >> 6;
    int c = lane & 15, rg = lane >> 4;

    FragU xv4[4];
    float xfl[4][8];
#pragma unroll
    for (int ti = 0; ti < 4; ++ti) {
        int row = (wave * 4 + ti) * 16 + c;
        xv4[ti].i = *(const int4v*)&xs_lds[row][rg * 8];
#pragma unroll
        for (int g2 = 0; g2 < 4; ++g2) {
            unsigned int u = (unsigned int)xv4[ti].i[g2];
            xfl[ti][2 * g2]     = __uint_as_float(u << 16);
            xfl[ti][2 * g2 + 1] = __uint_as_float(u & 0xffff0000u);
        }
    }

    f32x4 acc[4][4];
#pragma unroll
    for (int ti = 0; ti < 4; ++ti)
#pragma unroll
        for (int nb = 0; nb < 4; ++nb)
            acc[ti][nb] = (f32x4){0.f, 0.f, 0.f, 0.f};

    const int4v* Bg4 = (const int4v*)Bg;
#pragma unroll 2
    for (int kt = 0; kt < 25; ++kt) {
        FragU bf[4];
#pragma unroll
        for (int nb = 0; nb < 4; ++nb)
            bf[nb].i = Bg4[(kt * 4 + nb) * 64 + lane];
#pragma unroll
        for (int ti = 0; ti < 4; ++ti) {
            float hv = hid_lds[(wave * 4 + ti) * 16 + c][kt];
            FragU af;
            af.i.x = pk_bf16(hv * xfl[ti][0], hv * xfl[ti][1]);
            af.i.y = pk_bf16(hv * xfl[ti][2], hv * xfl[ti][3]);
            af.i.z = pk_bf16(hv * xfl[ti][4], hv * xfl[ti][5]);
            af.i.w = pk_bf16(hv * xfl[ti][6], hv * xfl[ti][7]);
#pragma unroll
            for (int nb = 0; nb < 4; ++nb)
                acc[ti][nb] = __builtin_amdgcn_mfma_f32_16x16x32_bf16(af.s, bf[nb].s, acc[ti][nb], 0, 0, 0);
        }
    }
    {   // kt = 25: b2 term, A = xs directly
        FragU bf[4];
#pragma unroll
        for (int nb = 0; nb < 4; ++nb)
            bf[nb].i = Bg4[(25 * 4 + nb) * 64 + lane];
#pragma unroll
        for (int ti = 0; ti < 4; ++ti)
#pragma unroll
            for (int nb = 0; nb < 4; ++nb)
                acc[ti][nb] = __builtin_amdgcn_mfma_f32_16x16x32_bf16(xv4[ti].s, bf[nb].s, acc[ti][nb], 0, 0, 0);
    }

    // epilogue: lane c holds channels (2c,2c+1) [nb 0,1] and (32+2c,32+2c+1) [nb 2,3]
#pragma unroll
    for (int ti = 0; ti < 4; ++ti) {
        int tl = wave * 4 + ti;
#pragma unroll
        for (int jj = 0; jj < 4; ++jj) {
            int le = tl * 16 + rg * 4 + jj;
            if (blockIdx.x * 256 + le < E2P) {
                unsigned short* dp = agg2b + (size_t)dst_lds[le] * C2;
                atomic_pk_bf16(dp + 2 * c,      pk_bf16(acc[ti][0][jj], acc[ti][1][jj]));
                atomic_pk_bf16(dp + 32 + 2 * c, pk_bf16(acc[ti][2][jj], acc[ti][3][jj]));
            }
        }
    }
}

// ---------------- finish conv2 (root2+bias2+elu), pool2 (pairwise max), per-graph mean
__global__ __launch_bounds__(256) void pool2_kernel(
    const unsigned short* __restrict__ agg2b, const unsigned short* __restrict__ x1b,
    const float* __restrict__ root2, const float* __restrict__ bias2,
    float* __restrict__ g)
{
    int b = blockIdx.x;
    int w = threadIdx.x >> 6, o = threadIdx.x & 63;
    __shared__ float part[4][C2];
    float sum = 0.f;
    for (int jj = w; jj < 50; jj += 4) {
        int j = b * 50 + jj;
        float hv[2];
#pragma unroll
        for (int t = 0; t < 2; ++t) {
            int n = 2 * j + t;
            float a = bf2f(agg2b[(size_t)n * C2 + o]) + bias2[o];
#pragma unroll
            for (int i = 0; i < C1; ++i)
                a = fmaf(bf2f(x1b[(size_t)n * C1 + i]), root2[i * C2 + o], a);
            hv[t] = elu1(a);
        }
        sum += fmaxf(hv[0], hv[1]);
    }
    part[w][o] = sum;
    __syncthreads();
    if (w == 0) {
        float s2 = part[0][o] + part[1][o] + part[2][o] + part[3][o];
        g[b * C2 + o] = s2 * (1.f / 50.f);
    }
}

// ---------------- FC head
__global__ __launch_bounds__(128) void head_kernel(
    const float* __restrict__ g,
    const float* __restrict__ fc1w, const float* __restrict__ fc1b,
    const float* __restrict__ fc2w, const float* __restrict__ fc2b,
    float* __restrict__ out)
{
    int b = blockIdx.x;
    int t = threadIdx.x;
    __shared__ float gs[C2];
    __shared__ float zs[128];
    __shared__ float ls[NCLS];
    if (t < C2) gs[t] = g[b * C2 + t];
    __syncthreads();
    float z = fc1b[t];
#pragma unroll
    for (int i = 0; i < C2; ++i) z = fmaf(gs[i], fc1w[i * 128 + t], z);
    zs[t] = elu1(z);
    __syncthreads();
    if (t < NCLS) {
        float l = fc2b[t];
#pragma unroll
        for (int k = 0; k < 128; ++k) l = fmaf(zs[k], fc2w[k * NCLS + t], l);
        ls[t] = l;
    }
    __syncthreads();
    if (t < NCLS) {
        float mx = ls[0];
#pragma unroll
        for (int c = 1; c < NCLS; ++c) mx = fmaxf(mx, ls[c]);
        float se = 0.f;
#pragma unroll
        for (int c = 0; c < NCLS; ++c) se += expf(ls[c] - mx);
        out[b * NCLS + t] = ls[t] - mx - logf(se);
    }
}

extern "C" void kernel_launch(void* const* d_in, const int* in_sizes, int n_in,
                              void* d_out, int out_size, void* d_ws, size_t ws_size,
                              hipStream_t stream)
{
    const float* x    = (const float*)d_in[0];
    const float* pos  = (const float*)d_in[1];
    const int*   ei   = (const int*)d_in[2];
    const float* ea   = (const float*)d_in[3];
    const int*   ei2  = (const int*)d_in[6];
    const float* n1w1 = (const float*)d_in[8];
    const float* n1b1 = (const float*)d_in[9];
    const float* n1w2 = (const float*)d_in[10];
    const float* n1b2 = (const float*)d_in[11];
    const float* root1= (const float*)d_in[12];
    const float* bias1= (const float*)d_in[13];
    const float* n2w1 = (const float*)d_in[14];
    const float* n2b1 = (const float*)d_in[15];
    const float* n2w2 = (const float*)d_in[16];
    const float* n2b2 = (const float*)d_in[17];
    const float* root2= (const float*)d_in[18];
    const float* bias2= (const float*)d_in[19];
    const float* fc1w = (const float*)d_in[20];
    const float* fc1b = (const float*)d_in[21];
    const float* fc2w = (const float*)d_in[22];
    const float* fc2b = (const float*)d_in[23];
    float* out = (float*)d_out;

    char* w = (char*)d_ws;
    unsigned short* agg1b = (unsigned short*)w;  w += (size_t)N_NODES * C1 * 2;   // 12.8 MB
    unsigned short* x1b   = (unsigned short*)w;  w += (size_t)N1P * C1 * 2;       // 6.4 MB
    float* pos1 = (float*)w;                     w += (size_t)N1P * 2 * 4;        // 0.8 MB
    unsigned int* maxbits = (unsigned int*)w;    w += 256;
    unsigned short* agg2b = (unsigned short*)w;  w += (size_t)N1P * C2 * 2;       // 12.8 MB
    float* g    = (float*)w;                     w += (size_t)BGR * C2 * 4;
    unsigned int* Bg = (unsigned int*)w;         w += 26624 * 4;
    unsigned int* W2f = (unsigned int*)w;        w += 512 * 4;
    int* cnt  = (int*)w;                         w += (size_t)N_NODES * 4;        // 0.8 MB
    int* offs = (int*)w;                         w += (size_t)N_NODES * 4;        // 0.8 MB
    int* cur  = (int*)w;                         w += (size_t)N_NODES * 4;        // 0.8 MB
    int* sorted_eid = (int*)w;                   w += (size_t)E1 * 4;             // 6.4 MB
    int* sorted_dst = (int*)w;                   w += (size_t)E1 * 4;             // 6.4 MB

    hipMemsetAsync(agg1b, 0, (size_t)N_NODES * C1 * 2, stream);
    hipMemsetAsync(agg2b, 0, (size_t)N1P * C2 * 2, stream);
    hipMemsetAsync(maxbits, 0, 256, stream);
    hipMemsetAsync(cnt, 0, (size_t)N_NODES * 4, stream);
    hipMemsetAsync(cur, 0, (size_t)N_NODES * 4, stream);

    bgbuild1_kernel<<<2, 256, 0, stream>>>(n1w2, n1b2, W2f);
    bgbuild_kernel<<<104, 256, 0, stream>>>(n2w2, n2b2, Bg);
    hist_kernel<<<E1 / 256, 256, 0, stream>>>(ei, cnt);
    scan_kernel<<<1, 1024, 0, stream>>>(cnt, offs);
    scatter_kernel<<<E1 / 256, 256, 0, stream>>>(ei, offs, cur, sorted_eid, sorted_dst);
    conv1_kernel<<<E1 / 256, 256, 0, stream>>>(x, ea, ei, n1w1, n1b1, W2f,
                                               sorted_eid, sorted_dst, agg1b);
    pool1_kernel<<<(N1P * C1 + 255) / 256, 256, 0, stream>>>(agg1b, x, root1, bias1, pos, x1b, pos1);
    maxabs_kernel<<<(E2P + 255) / 256, 256, 0, stream>>>(ei2, pos1, maxbits);
    conv2_kernel<<<(E2P + 255) / 256, 256, 0, stream>>>(ei2, pos1, x1b, n2w1, n2b1, maxbits, Bg, agg2b);
    pool2_kernel<<<BGR, 256, 0, stream>>>(agg2b, x1b, root2, bias2, g);
    head_kernel<<<BGR, 128, 0, stream>>>(g, fc1w, fc1b, fc2w, fc2b, out);
}

// Round 7
// 186.478 us; speedup vs baseline: 3.8388x; 3.8388x over previous
//
#include <hip/hip_runtime.h>
#include <hip/hip_bf16.h>

#define N_NODES 200000
#define E1 1600000
#define N1P 100000
#define E2P 100000
#define N2P 50000
#define BGR 1000
#define C1 32
#define C2 64
#define HIDN 25
#define NCLS 10

typedef short short8 __attribute__((ext_vector_type(8)));
typedef int int4v __attribute__((ext_vector_type(4)));
typedef float f32x4 __attribute__((ext_vector_type(4)));
typedef float f32x2 __attribute__((ext_vector_type(2)));

union FragU { int4v i; short8 s; };

__device__ __forceinline__ float elu1(float v) {
    return v > 0.f ? v : expm1f(v);
}
__device__ __forceinline__ float bf2f(unsigned short u) {
    return __uint_as_float(((unsigned int)u) << 16);
}
__device__ __forceinline__ unsigned int pk_bf16(float a, float b) {
    unsigned int r;
    asm("v_cvt_pk_bf16_f32 %0, %1, %2" : "=v"(r) : "v"(a), "v"(b));
    return r;
}
__device__ __forceinline__ void atomic_pk_bf16(unsigned short* p, unsigned int pk) {
    asm volatile("global_atomic_pk_add_bf16 %0, %1, off" :: "v"(p), "v"(pk) : "memory");
}

// ---------------- fused fragment builders
// blk 0-1:  conv1 B [32][32] (rows 0-24 w2, 25 b2, 26-31 zero), even/odd col perm:
//           MFMA m, col c -> channel 2c+m.  W2f[(m*64+lane)*4+slot]
// blk 2+:   conv2 B [832][64], col perm: MFMA nb, col c -> ch (nb>>1)*32 + 2c + (nb&1)
__global__ __launch_bounds__(256) void bgbuild_kernel(
    const float* __restrict__ w2a, const float* __restrict__ b2a,
    const float* __restrict__ w2b, const float* __restrict__ b2b,
    unsigned int* __restrict__ W2f, unsigned int* __restrict__ Bg)
{
    int blk = blockIdx.x, t = threadIdx.x;
    if (blk < 2) {
        int q = blk * 256 + t;                  // 512 u32 total
        int jj = q & 3, l = (q >> 2) & 63, m = q >> 8;
        int k0 = (l >> 4) * 8 + 2 * jj;
        int o = 2 * (l & 15) + m;
        float v0 = (k0 < 25) ? w2a[k0 * 32 + o] : (k0 == 25 ? b2a[o] : 0.f);
        int k1 = k0 + 1;
        float v1 = (k1 < 25) ? w2a[k1 * 32 + o] : (k1 == 25 ? b2a[o] : 0.f);
        W2f[q] = pk_bf16(v0, v1);
    } else {
        int idx = (blk - 2) * 256 + t;          // 26624 pairs
        if (idx >= 26 * 4 * 64 * 4) return;
        int g0 = idx * 2;
        int j = g0 & 7;
        int l = (g0 >> 3) & 63;
        int nb = (g0 >> 9) & 3;
        int kt = g0 >> 11;
        int k = kt * 32 + (l >> 4) * 8 + j;
        int o = (nb >> 1) * 32 + 2 * (l & 15) + (nb & 1);
        float v0, v1;
        if (k < 800) { v0 = w2b[k * 64 + o]; v1 = w2b[(k + 1) * 64 + o]; }
        else         { v0 = b2b[(k - 800) * 64 + o]; v1 = b2b[(k - 799) * 64 + o]; }
        Bg[idx] = pk_bf16(v0, v1);
    }
}

// ---------------- conv1 via MFMA; epilogue = packed bf16 atomics, full 64B row/instr
__global__ __launch_bounds__(256) void conv1_kernel(
    const float* __restrict__ x, const float* __restrict__ ea,
    const int* __restrict__ ei,
    const float* __restrict__ w1, const float* __restrict__ b1,
    const unsigned int* __restrict__ W2f,
    unsigned short* __restrict__ agg1b)
{
    __shared__ unsigned int afrag[16][4][64];   // 16 KB
    __shared__ int dst_lds[256];

    int t = threadIdx.x;
    int e = blockIdx.x * 256 + t;               // E1 % 256 == 0
    f32x2 a = ((const f32x2*)ea)[e];
    int s = ei[e], d = ei[E1 + e];
    float xv = x[s];
    dst_lds[t] = d;

    float v[26];
#pragma unroll
    for (int h = 0; h < HIDN; ++h) {
        float u = fmaf(a.x, w1[h], fmaf(a.y, w1[HIDN + h], b1[h]));
        v[h] = fmaxf(u, 0.f) * xv;
    }
    v[25] = xv;

    int tile = t >> 4, r16 = t & 15;
#pragma unroll
    for (int p = 0; p < 13; ++p) {              // pair p covers k = 2p, 2p+1
        int g = p >> 2, j = p & 3;
        afrag[tile][j][g * 16 + r16] = pk_bf16(v[2 * p], v[2 * p + 1]);
    }
    afrag[tile][1][48 + r16] = 0;               // k = 26..31 zero
    afrag[tile][2][48 + r16] = 0;
    afrag[tile][3][48 + r16] = 0;
    __syncthreads();

    int lane = t & 63, wave = t >> 6;
    FragU bf0, bf1;
    bf0.i = *(const int4v*)(W2f + lane * 4);
    bf1.i = *(const int4v*)(W2f + (64 + lane) * 4);
    int c = lane & 15, rg = lane >> 4;

#pragma unroll
    for (int ti = 0; ti < 4; ++ti) {
        int tl = wave * 4 + ti;
        FragU af;
        af.i.x = afrag[tl][0][lane];
        af.i.y = afrag[tl][1][lane];
        af.i.z = afrag[tl][2][lane];
        af.i.w = afrag[tl][3][lane];
        f32x4 a0 = (f32x4){0.f, 0.f, 0.f, 0.f};
        f32x4 a1 = (f32x4){0.f, 0.f, 0.f, 0.f};
        a0 = __builtin_amdgcn_mfma_f32_16x16x32_bf16(af.s, bf0.s, a0, 0, 0, 0);
        a1 = __builtin_amdgcn_mfma_f32_16x16x32_bf16(af.s, bf1.s, a1, 0, 0, 0);
#pragma unroll
        for (int jj = 0; jj < 4; ++jj) {
            int le = tl * 16 + rg * 4 + jj;
            // lane c holds channels (2c, 2c+1) -> one pk atomic, rows fully covered
            atomic_pk_bf16(agg1b + (size_t)dst_lds[le] * C1 + 2 * c,
                           pk_bf16(a0[jj], a1[jj]));
        }
    }
}

// ---------------- finish conv1 (root+bias+elu) and pool1 (pairwise max) + pos mean
__global__ __launch_bounds__(256) void pool1_kernel(
    const unsigned short* __restrict__ agg1b, const float* __restrict__ x,
    const float* __restrict__ root1, const float* __restrict__ bias1,
    const float* __restrict__ pos, unsigned short* __restrict__ x1b,
    float* __restrict__ pos1)
{
    int t = blockIdx.x * blockDim.x + threadIdx.x;
    if (t >= N1P * C1) return;
    int j = t >> 5, o = t & 31;
    int na = 2 * j, nb = 2 * j + 1;
    float r = root1[o], bo = bias1[o];
    float ha = elu1(bf2f(agg1b[(size_t)na * C1 + o]) + x[na] * r + bo);
    float hb = elu1(bf2f(agg1b[(size_t)nb * C1 + o]) + x[nb] * r + bo);
    float mx = fmaxf(ha, hb);
    x1b[t] = (unsigned short)(pk_bf16(mx, mx) & 0xffffu);
    if (o < 2) pos1[j * 2 + o] = 0.5f * (pos[na * 2 + o] + pos[nb * 2 + o]);
}

// ---------------- global max|cart| over pooled edges
__global__ __launch_bounds__(256) void maxabs_kernel(
    const int* __restrict__ ei2, const float* __restrict__ pos1,
    unsigned int* __restrict__ maxbits)
{
    int e = blockIdx.x * blockDim.x + threadIdx.x;
    float m = 0.f;
    if (e < E2P) {
        int s = ei2[e], d = ei2[E2P + e];
        float c0 = pos1[2 * s] - pos1[2 * d];
        float c1 = pos1[2 * s + 1] - pos1[2 * d + 1];
        m = fmaxf(fabsf(c0), fabsf(c1));
    }
#pragma unroll
    for (int off = 32; off; off >>= 1)
        m = fmaxf(m, __shfl_down(m, off));
    if ((threadIdx.x & 63) == 0)
        atomicMax(maxbits, __float_as_uint(m));
}

// ---------------- conv2 via MFMA: 128 edges/block (782 blocks), bf16 hid in LDS,
// software-prefetched B fragments, pk-bf16 atomic epilogue
__global__ __launch_bounds__(256) void conv2_kernel(
    const int* __restrict__ ei2, const float* __restrict__ pos1,
    const unsigned short* __restrict__ x1b,
    const float* __restrict__ w1, const float* __restrict__ b1,
    const unsigned int* __restrict__ maxbits,
    const unsigned int* __restrict__ Bg,
    unsigned short* __restrict__ agg2b)
{
    __shared__ __align__(16) unsigned short xs_lds[128][40];  // 10.2 KB
    __shared__ unsigned int hidb[128][14];                     // 7.2 KB (13 pairs+pad)
    __shared__ int dst_lds[128];

    int t = threadIdx.x;
    int base = blockIdx.x * 128;

    if (t < 128) {   // stage one edge per thread
        int ge = base + t;
        bool ok = ge < E2P;
        float inv = 0.5f / __uint_as_float(maxbits[0]);
        int s = 0, d = 0;
        if (ok) { s = ei2[ge]; d = ei2[E2P + ge]; }
        dst_lds[t] = d;
        float a0 = (pos1[2 * s] - pos1[2 * d]) * inv + 0.5f;
        float a1 = (pos1[2 * s + 1] - pos1[2 * d + 1]) * inv + 0.5f;
        float hv[26];
#pragma unroll
        for (int h = 0; h < HIDN; ++h) {
            float u = fmaf(a0, w1[h], fmaf(a1, w1[HIDN + h], b1[h]));
            hv[h] = ok ? fmaxf(u, 0.f) : 0.f;
        }
        hv[25] = 0.f;
#pragma unroll
        for (int p = 0; p < 13; ++p)
            hidb[t][p] = pk_bf16(hv[2 * p], hv[2 * p + 1]);
        const int4v* xp = (const int4v*)(x1b + (size_t)s * C1);
#pragma unroll
        for (int q = 0; q < 4; ++q) {
            int4v z4 = (int4v){0, 0, 0, 0};
            *(int4v*)&xs_lds[t][q * 8] = ok ? xp[q] : z4;
        }
    }
    __syncthreads();

    int lane = t & 63, wave = t >> 6;
    int c = lane & 15, rg = lane >> 4;

    FragU xv2[2];
    float xfl[2][8];
#pragma unroll
    for (int ti = 0; ti < 2; ++ti) {
        int row = (wave * 2 + ti) * 16 + c;
        xv2[ti].i = *(const int4v*)&xs_lds[row][rg * 8];
#pragma unroll
        for (int g2 = 0; g2 < 4; ++g2) {
            unsigned int u = (unsigned int)xv2[ti].i[g2];
            xfl[ti][2 * g2]     = __uint_as_float(u << 16);
            xfl[ti][2 * g2 + 1] = __uint_as_float(u & 0xffff0000u);
        }
    }

    f32x4 acc[2][4];
#pragma unroll
    for (int ti = 0; ti < 2; ++ti)
#pragma unroll
        for (int nb = 0; nb < 4; ++nb)
            acc[ti][nb] = (f32x4){0.f, 0.f, 0.f, 0.f};

    const int4v* Bg4 = (const int4v*)Bg;
    FragU bf[4];
#pragma unroll
    for (int nb = 0; nb < 4; ++nb)
        bf[nb].i = Bg4[nb * 64 + lane];          // kt = 0

#pragma unroll
    for (int kt = 0; kt < 25; ++kt) {
        FragU bn[4];                             // prefetch kt+1 (kt=24 -> b2 frags)
#pragma unroll
        for (int nb = 0; nb < 4; ++nb)
            bn[nb].i = Bg4[((kt + 1) * 4 + nb) * 64 + lane];
#pragma unroll
        for (int ti = 0; ti < 2; ++ti) {
            unsigned int hu = hidb[(wave * 2 + ti) * 16 + c][kt >> 1];
            float hvv = bf2f((unsigned short)((kt & 1) ? (hu >> 16) : (hu & 0xffffu)));
            FragU af;
            af.i.x = pk_bf16(hvv * xfl[ti][0], hvv * xfl[ti][1]);
            af.i.y = pk_bf16(hvv * xfl[ti][2], hvv * xfl[ti][3]);
            af.i.z = pk_bf16(hvv * xfl[ti][4], hvv * xfl[ti][5]);
            af.i.w = pk_bf16(hvv * xfl[ti][6], hvv * xfl[ti][7]);
#pragma unroll
            for (int nb = 0; nb < 4; ++nb)
                acc[ti][nb] = __builtin_amdgcn_mfma_f32_16x16x32_bf16(af.s, bf[nb].s, acc[ti][nb], 0, 0, 0);
        }
#pragma unroll
        for (int nb = 0; nb < 4; ++nb) bf[nb] = bn[nb];
    }
    // kt = 25: b2 term, A = xs directly
#pragma unroll
    for (int ti = 0; ti < 2; ++ti)
#pragma unroll
        for (int nb = 0; nb < 4; ++nb)
            acc[ti][nb] = __builtin_amdgcn_mfma_f32_16x16x32_bf16(xv2[ti].s, bf[nb].s, acc[ti][nb], 0, 0, 0);

    // epilogue: lane c holds channels (2c,2c+1) [nb 0,1] and (32+2c,32+2c+1) [nb 2,3]
#pragma unroll
    for (int ti = 0; ti < 2; ++ti) {
        int tl = wave * 2 + ti;
#pragma unroll
        for (int jj = 0; jj < 4; ++jj) {
            int le = tl * 16 + rg * 4 + jj;
            if (base + le < E2P) {
                unsigned short* dp = agg2b + (size_t)dst_lds[le] * C2;
                atomic_pk_bf16(dp + 2 * c,      pk_bf16(acc[ti][0][jj], acc[ti][1][jj]));
                atomic_pk_bf16(dp + 32 + 2 * c, pk_bf16(acc[ti][2][jj], acc[ti][3][jj]));
            }
        }
    }
}

// ---------------- fused: finish conv2 (root2+bias2+elu), pool2 (pairwise max),
// per-graph mean, then FC head + log_softmax
__global__ __launch_bounds__(256) void pool2_head_kernel(
    const unsigned short* __restrict__ agg2b, const unsigned short* __restrict__ x1b,
    const float* __restrict__ root2, const float* __restrict__ bias2,
    const float* __restrict__ fc1w, const float* __restrict__ fc1b,
    const float* __restrict__ fc2w, const float* __restrict__ fc2b,
    float* __restrict__ out)
{
    int b = blockIdx.x;
    int t = threadIdx.x;
    int w = t >> 6, o = t & 63;
    __shared__ float part[4][C2];
    __shared__ float gs[C2];
    __shared__ float zs[128];
    __shared__ float ls[NCLS];

    float sum = 0.f;
    for (int jj = w; jj < 50; jj += 4) {
        int j = b * 50 + jj;
        float hv[2];
#pragma unroll
        for (int tt = 0; tt < 2; ++tt) {
            int n = 2 * j + tt;
            float a = bf2f(agg2b[(size_t)n * C2 + o]) + bias2[o];
#pragma unroll
            for (int i = 0; i < C1; ++i)
                a = fmaf(bf2f(x1b[(size_t)n * C1 + i]), root2[i * C2 + o], a);
            hv[tt] = elu1(a);
        }
        sum += fmaxf(hv[0], hv[1]);
    }
    part[w][o] = sum;
    __syncthreads();
    if (w == 0)
        gs[o] = (part[0][o] + part[1][o] + part[2][o] + part[3][o]) * (1.f / 50.f);
    __syncthreads();
    if (t < 128) {
        float z = fc1b[t];
#pragma unroll
        for (int i = 0; i < C2; ++i) z = fmaf(gs[i], fc1w[i * 128 + t], z);
        zs[t] = elu1(z);
    }
    __syncthreads();
    if (t < NCLS) {
        float l = fc2b[t];
#pragma unroll
        for (int k = 0; k < 128; ++k) l = fmaf(zs[k], fc2w[k * NCLS + t], l);
        ls[t] = l;
    }
    __syncthreads();
    if (t < NCLS) {
        float mx = ls[0];
#pragma unroll
        for (int cc = 1; cc < NCLS; ++cc) mx = fmaxf(mx, ls[cc]);
        float se = 0.f;
#pragma unroll
        for (int cc = 0; cc < NCLS; ++cc) se += expf(ls[cc] - mx);
        out[b * NCLS + t] = ls[t] - mx - logf(se);
    }
}

extern "C" void kernel_launch(void* const* d_in, const int* in_sizes, int n_in,
                              void* d_out, int out_size, void* d_ws, size_t ws_size,
                              hipStream_t stream)
{
    const float* x    = (const float*)d_in[0];
    const float* pos  = (const float*)d_in[1];
    const int*   ei   = (const int*)d_in[2];
    const float* ea   = (const float*)d_in[3];
    const int*   ei2  = (const int*)d_in[6];
    const float* n1w1 = (const float*)d_in[8];
    const float* n1b1 = (const float*)d_in[9];
    const float* n1w2 = (const float*)d_in[10];
    const float* n1b2 = (const float*)d_in[11];
    const float* root1= (const float*)d_in[12];
    const float* bias1= (const float*)d_in[13];
    const float* n2w1 = (const float*)d_in[14];
    const float* n2b1 = (const float*)d_in[15];
    const float* n2w2 = (const float*)d_in[16];
    const float* n2b2 = (const float*)d_in[17];
    const float* root2= (const float*)d_in[18];
    const float* bias2= (const float*)d_in[19];
    const float* fc1w = (const float*)d_in[20];
    const float* fc1b = (const float*)d_in[21];
    const float* fc2w = (const float*)d_in[22];
    const float* fc2b = (const float*)d_in[23];
    float* out = (float*)d_out;

    char* w = (char*)d_ws;
    unsigned short* agg1b = (unsigned short*)w;  w += (size_t)N_NODES * C1 * 2;   // 12.8 MB
    unsigned short* x1b   = (unsigned short*)w;  w += (size_t)N1P * C1 * 2;       // 6.4 MB
    float* pos1 = (float*)w;                     w += (size_t)N1P * 2 * 4;        // 0.8 MB
    unsigned int* maxbits = (unsigned int*)w;    w += 256;
    unsigned short* agg2b = (unsigned short*)w;  w += (size_t)N1P * C2 * 2;       // 12.8 MB
    unsigned int* Bg = (unsigned int*)w;         w += 26624 * 4;
    unsigned int* W2f = (unsigned int*)w;        w += 512 * 4;

    hipMemsetAsync(agg1b, 0, (size_t)N_NODES * C1 * 2, stream);
    hipMemsetAsync(agg2b, 0, (size_t)N1P * C2 * 2, stream);
    hipMemsetAsync(maxbits, 0, 256, stream);

    bgbuild_kernel<<<106, 256, 0, stream>>>(n1w2, n1b2, n2w2, n2b2, W2f, Bg);
    conv1_kernel<<<E1 / 256, 256, 0, stream>>>(x, ea, ei, n1w1, n1b1, W2f, agg1b);
    pool1_kernel<<<(N1P * C1 + 255) / 256, 256, 0, stream>>>(agg1b, x, root1, bias1, pos, x1b, pos1);
    maxabs_kernel<<<(E2P + 255) / 256, 256, 0, stream>>>(ei2, pos1, maxbits);
    conv2_kernel<<<(E2P + 127) / 128, 256, 0, stream>>>(ei2, pos1, x1b, n2w1, n2b1, maxbits, Bg, agg2b);
    pool2_head_kernel<<<BGR, 256, 0, stream>>>(agg2b, x1b, root2, bias2,
                                               fc1w, fc1b, fc2w, fc2b, out);
}

// Round 9
// 185.952 us; speedup vs baseline: 3.8497x; 1.0028x over previous
//
#include <hip/hip_runtime.h>
#include <hip/hip_bf16.h>

#define N_NODES 200000
#define E1 1600000
#define N1P 100000
#define E2P 100000
#define N2P 50000
#define BGR 1000
#define C1 32
#define C2 64
#define HIDN 25
#define NCLS 10

typedef short short8 __attribute__((ext_vector_type(8)));
typedef int int4v __attribute__((ext_vector_type(4)));
typedef float f32x4 __attribute__((ext_vector_type(4)));
typedef float f32x2 __attribute__((ext_vector_type(2)));

union FragU { int4v i; short8 s; };

__device__ __forceinline__ float elu1(float v) {
    return v > 0.f ? v : expm1f(v);
}
__device__ __forceinline__ float bf2f(unsigned short u) {
    return __uint_as_float(((unsigned int)u) << 16);
}
__device__ __forceinline__ unsigned int pk_bf16(float a, float b) {
    unsigned int r;
    asm("v_cvt_pk_bf16_f32 %0, %1, %2" : "=v"(r) : "v"(a), "v"(b));
    return r;
}
__device__ __forceinline__ void atomic_pk_bf16(unsigned short* p, unsigned int pk) {
    asm volatile("global_atomic_pk_add_bf16 %0, %1, off" :: "v"(p), "v"(pk) : "memory");
}

// ---------------- fused fragment builders
// blk 0-1:  conv1 B [32][32] (rows 0-24 w2, 25 b2, 26-31 zero), even/odd col perm:
//           MFMA m, col c -> channel 2c+m.  W2f[(m*64+lane)*4+slot]
// blk 2+:   conv2 B [832][64], col perm: MFMA nb, col c -> ch (nb>>1)*32 + 2c + (nb&1)
__global__ __launch_bounds__(256) void bgbuild_kernel(
    const float* __restrict__ w2a, const float* __restrict__ b2a,
    const float* __restrict__ w2b, const float* __restrict__ b2b,
    unsigned int* __restrict__ W2f, unsigned int* __restrict__ Bg)
{
    int blk = blockIdx.x, t = threadIdx.x;
    if (blk < 2) {
        int q = blk * 256 + t;                  // 512 u32 total
        int jj = q & 3, l = (q >> 2) & 63, m = q >> 8;
        int k0 = (l >> 4) * 8 + 2 * jj;
        int o = 2 * (l & 15) + m;
        float v0 = (k0 < 25) ? w2a[k0 * 32 + o] : (k0 == 25 ? b2a[o] : 0.f);
        int k1 = k0 + 1;
        float v1 = (k1 < 25) ? w2a[k1 * 32 + o] : (k1 == 25 ? b2a[o] : 0.f);
        W2f[q] = pk_bf16(v0, v1);
    } else {
        int idx = (blk - 2) * 256 + t;          // 26624 pairs
        if (idx >= 26 * 4 * 64 * 4) return;
        int g0 = idx * 2;
        int j = g0 & 7;
        int l = (g0 >> 3) & 63;
        int nb = (g0 >> 9) & 3;
        int kt = g0 >> 11;
        int k = kt * 32 + (l >> 4) * 8 + j;
        int o = (nb >> 1) * 32 + 2 * (l & 15) + (nb & 1);
        float v0, v1;
        if (k < 800) { v0 = w2b[k * 64 + o]; v1 = w2b[(k + 1) * 64 + o]; }
        else         { v0 = b2b[(k - 800) * 64 + o]; v1 = b2b[(k - 799) * 64 + o]; }
        Bg[idx] = pk_bf16(v0, v1);
    }
}

// ---------------- conv1 via MFMA; agg sharded by blockIdx parity (atomic-wall probe)
__global__ __launch_bounds__(256) void conv1_kernel(
    const float* __restrict__ x, const float* __restrict__ ea,
    const int* __restrict__ ei,
    const float* __restrict__ w1, const float* __restrict__ b1,
    const unsigned int* __restrict__ W2f,
    unsigned short* __restrict__ agg1b)
{
    __shared__ unsigned int afrag[16][4][64];   // 16 KB
    __shared__ int dst_lds[256];

    int t = threadIdx.x;
    int e = blockIdx.x * 256 + t;               // E1 % 256 == 0
    unsigned short* aggp = agg1b + ((blockIdx.x & 1) ? (size_t)N_NODES * C1 : (size_t)0);
    f32x2 a = ((const f32x2*)ea)[e];
    int s = ei[e], d = ei[E1 + e];
    float xv = x[s];
    dst_lds[t] = d;

    float v[26];
#pragma unroll
    for (int h = 0; h < HIDN; ++h) {
        float u = fmaf(a.x, w1[h], fmaf(a.y, w1[HIDN + h], b1[h]));
        v[h] = fmaxf(u, 0.f) * xv;
    }
    v[25] = xv;

    int tile = t >> 4, r16 = t & 15;
#pragma unroll
    for (int p = 0; p < 13; ++p) {              // pair p covers k = 2p, 2p+1
        int g = p >> 2, j = p & 3;
        afrag[tile][j][g * 16 + r16] = pk_bf16(v[2 * p], v[2 * p + 1]);
    }
    afrag[tile][1][48 + r16] = 0;               // k = 26..31 zero
    afrag[tile][2][48 + r16] = 0;
    afrag[tile][3][48 + r16] = 0;
    __syncthreads();

    int lane = t & 63, wave = t >> 6;
    FragU bf0, bf1;
    bf0.i = *(const int4v*)(W2f + lane * 4);
    bf1.i = *(const int4v*)(W2f + (64 + lane) * 4);
    int c = lane & 15, rg = lane >> 4;

#pragma unroll
    for (int ti = 0; ti < 4; ++ti) {
        int tl = wave * 4 + ti;
        FragU af;
        af.i.x = afrag[tl][0][lane];
        af.i.y = afrag[tl][1][lane];
        af.i.z = afrag[tl][2][lane];
        af.i.w = afrag[tl][3][lane];
        f32x4 a0 = (f32x4){0.f, 0.f, 0.f, 0.f};
        f32x4 a1 = (f32x4){0.f, 0.f, 0.f, 0.f};
        a0 = __builtin_amdgcn_mfma_f32_16x16x32_bf16(af.s, bf0.s, a0, 0, 0, 0);
        a1 = __builtin_amdgcn_mfma_f32_16x16x32_bf16(af.s, bf1.s, a1, 0, 0, 0);
#pragma unroll
        for (int jj = 0; jj < 4; ++jj) {
            int le = tl * 16 + rg * 4 + jj;
            // lane c holds channels (2c, 2c+1) -> one pk atomic, rows fully covered
            atomic_pk_bf16(aggp + (size_t)dst_lds[le] * C1 + 2 * c,
                           pk_bf16(a0[jj], a1[jj]));
        }
    }
}

// ---------------- finish conv1 (sum shards, root+bias+elu) and pool1 + pos mean
__global__ __launch_bounds__(256) void pool1_kernel(
    const unsigned short* __restrict__ agg1b, const float* __restrict__ x,
    const float* __restrict__ root1, const float* __restrict__ bias1,
    const float* __restrict__ pos, unsigned short* __restrict__ x1b,
    float* __restrict__ pos1)
{
    int t = blockIdx.x * blockDim.x + threadIdx.x;
    if (t >= N1P * C1) return;
    int j = t >> 5, o = t & 31;
    int na = 2 * j, nb = 2 * j + 1;
    const unsigned short* c0 = agg1b;
    const unsigned short* c1 = agg1b + (size_t)N_NODES * C1;
    float r = root1[o], bo = bias1[o];
    float sa = bf2f(c0[(size_t)na * C1 + o]) + bf2f(c1[(size_t)na * C1 + o]);
    float sb = bf2f(c0[(size_t)nb * C1 + o]) + bf2f(c1[(size_t)nb * C1 + o]);
    float ha = elu1(sa + x[na] * r + bo);
    float hb = elu1(sb + x[nb] * r + bo);
    float mx = fmaxf(ha, hb);
    x1b[t] = (unsigned short)(pk_bf16(mx, mx) & 0xffffu);
    if (o < 2) pos1[j * 2 + o] = 0.5f * (pos[na * 2 + o] + pos[nb * 2 + o]);
}

// ---------------- global max|cart| over pooled edges
__global__ __launch_bounds__(256) void maxabs_kernel(
    const int* __restrict__ ei2, const float* __restrict__ pos1,
    unsigned int* __restrict__ maxbits)
{
    int e = blockIdx.x * blockDim.x + threadIdx.x;
    float m = 0.f;
    if (e < E2P) {
        int s = ei2[e], d = ei2[E2P + e];
        float c0 = pos1[2 * s] - pos1[2 * d];
        float c1 = pos1[2 * s + 1] - pos1[2 * d + 1];
        m = fmaxf(fabsf(c0), fabsf(c1));
    }
#pragma unroll
    for (int off = 32; off; off >>= 1)
        m = fmaxf(m, __shfl_down(m, off));
    if ((threadIdx.x & 63) == 0)
        atomicMax(maxbits, __float_as_uint(m));
}

// ---------------- conv2 via MFMA: 128 edges/block (782 blocks), bf16 hid in LDS,
// software-prefetched B fragments, pk-bf16 atomic epilogue  [round-7 exact]
__global__ __launch_bounds__(256) void conv2_kernel(
    const int* __restrict__ ei2, const float* __restrict__ pos1,
    const unsigned short* __restrict__ x1b,
    const float* __restrict__ w1, const float* __restrict__ b1,
    const unsigned int* __restrict__ maxbits,
    const unsigned int* __restrict__ Bg,
    unsigned short* __restrict__ agg2b)
{
    __shared__ __align__(16) unsigned short xs_lds[128][40];  // 10.2 KB
    __shared__ unsigned int hidb[128][14];                     // 7.2 KB (13 pairs+pad)
    __shared__ int dst_lds[128];

    int t = threadIdx.x;
    int base = blockIdx.x * 128;

    if (t < 128) {   // stage one edge per thread
        int ge = base + t;
        bool ok = ge < E2P;
        float inv = 0.5f / __uint_as_float(maxbits[0]);
        int s = 0, d = 0;
        if (ok) { s = ei2[ge]; d = ei2[E2P + ge]; }
        dst_lds[t] = d;
        float a0 = (pos1[2 * s] - pos1[2 * d]) * inv + 0.5f;
        float a1 = (pos1[2 * s + 1] - pos1[2 * d + 1]) * inv + 0.5f;
        float hv[26];
#pragma unroll
        for (int h = 0; h < HIDN; ++h) {
            float u = fmaf(a0, w1[h], fmaf(a1, w1[HIDN + h], b1[h]));
            hv[h] = ok ? fmaxf(u, 0.f) : 0.f;
        }
        hv[25] = 0.f;
#pragma unroll
        for (int p = 0; p < 13; ++p)
            hidb[t][p] = pk_bf16(hv[2 * p], hv[2 * p + 1]);
        const int4v* xp = (const int4v*)(x1b + (size_t)s * C1);
#pragma unroll
        for (int q = 0; q < 4; ++q) {
            int4v z4 = (int4v){0, 0, 0, 0};
            *(int4v*)&xs_lds[t][q * 8] = ok ? xp[q] : z4;
        }
    }
    __syncthreads();

    int lane = t & 63, wave = t >> 6;
    int c = lane & 15, rg = lane >> 4;

    FragU xv2[2];
    float xfl[2][8];
#pragma unroll
    for (int ti = 0; ti < 2; ++ti) {
        int row = (wave * 2 + ti) * 16 + c;
        xv2[ti].i = *(const int4v*)&xs_lds[row][rg * 8];
#pragma unroll
        for (int g2 = 0; g2 < 4; ++g2) {
            unsigned int u = (unsigned int)xv2[ti].i[g2];
            xfl[ti][2 * g2]     = __uint_as_float(u << 16);
            xfl[ti][2 * g2 + 1] = __uint_as_float(u & 0xffff0000u);
        }
    }

    f32x4 acc[2][4];
#pragma unroll
    for (int ti = 0; ti < 2; ++ti)
#pragma unroll
        for (int nb = 0; nb < 4; ++nb)
            acc[ti][nb] = (f32x4){0.f, 0.f, 0.f, 0.f};

    const int4v* Bg4 = (const int4v*)Bg;
    FragU bf[4];
#pragma unroll
    for (int nb = 0; nb < 4; ++nb)
        bf[nb].i = Bg4[nb * 64 + lane];          // kt = 0

#pragma unroll
    for (int kt = 0; kt < 25; ++kt) {
        FragU bn[4];                             // prefetch kt+1 (kt=24 -> b2 frags)
#pragma unroll
        for (int nb = 0; nb < 4; ++nb)
            bn[nb].i = Bg4[((kt + 1) * 4 + nb) * 64 + lane];
#pragma unroll
        for (int ti = 0; ti < 2; ++ti) {
            unsigned int hu = hidb[(wave * 2 + ti) * 16 + c][kt >> 1];
            float hvv = bf2f((unsigned short)((kt & 1) ? (hu >> 16) : (hu & 0xffffu)));
            FragU af;
            af.i.x = pk_bf16(hvv * xfl[ti][0], hvv * xfl[ti][1]);
            af.i.y = pk_bf16(hvv * xfl[ti][2], hvv * xfl[ti][3]);
            af.i.z = pk_bf16(hvv * xfl[ti][4], hvv * xfl[ti][5]);
            af.i.w = pk_bf16(hvv * xfl[ti][6], hvv * xfl[ti][7]);
#pragma unroll
            for (int nb = 0; nb < 4; ++nb)
                acc[ti][nb] = __builtin_amdgcn_mfma_f32_16x16x32_bf16(af.s, bf[nb].s, acc[ti][nb], 0, 0, 0);
        }
#pragma unroll
        for (int nb = 0; nb < 4; ++nb) bf[nb] = bn[nb];
    }
    // kt = 25: b2 term, A = xs directly
#pragma unroll
    for (int ti = 0; ti < 2; ++ti)
#pragma unroll
        for (int nb = 0; nb < 4; ++nb)
            acc[ti][nb] = __builtin_amdgcn_mfma_f32_16x16x32_bf16(xv2[ti].s, bf[nb].s, acc[ti][nb], 0, 0, 0);

    // epilogue: lane c holds channels (2c,2c+1) [nb 0,1] and (32+2c,32+2c+1) [nb 2,3]
#pragma unroll
    for (int ti = 0; ti < 2; ++ti) {
        int tl = wave * 2 + ti;
#pragma unroll
        for (int jj = 0; jj < 4; ++jj) {
            int le = tl * 16 + rg * 4 + jj;
            if (base + le < E2P) {
                unsigned short* dp = agg2b + (size_t)dst_lds[le] * C2;
                atomic_pk_bf16(dp + 2 * c,      pk_bf16(acc[ti][0][jj], acc[ti][1][jj]));
                atomic_pk_bf16(dp + 32 + 2 * c, pk_bf16(acc[ti][2][jj], acc[ti][3][jj]));
            }
        }
    }
}

// ---------------- fused: finish conv2 (root2+bias2+elu), pool2 (pairwise max),
// per-graph mean, then FC head + log_softmax  [round-7 exact]
__global__ __launch_bounds__(256) void pool2_head_kernel(
    const unsigned short* __restrict__ agg2b, const unsigned short* __restrict__ x1b,
    const float* __restrict__ root2, const float* __restrict__ bias2,
    const float* __restrict__ fc1w, const float* __restrict__ fc1b,
    const float* __restrict__ fc2w, const float* __restrict__ fc2b,
    float* __restrict__ out)
{
    int b = blockIdx.x;
    int t = threadIdx.x;
    int w = t >> 6, o = t & 63;
    __shared__ float part[4][C2];
    __shared__ float gs[C2];
    __shared__ float zs[128];
    __shared__ float ls[NCLS];

    float sum = 0.f;
    for (int jj = w; jj < 50; jj += 4) {
        int j = b * 50 + jj;
        float hv[2];
#pragma unroll
        for (int tt = 0; tt < 2; ++tt) {
            int n = 2 * j + tt;
            float a = bf2f(agg2b[(size_t)n * C2 + o]) + bias2[o];
#pragma unroll
            for (int i = 0; i < C1; ++i)
                a = fmaf(bf2f(x1b[(size_t)n * C1 + i]), root2[i * C2 + o], a);
            hv[tt] = elu1(a);
        }
        sum += fmaxf(hv[0], hv[1]);
    }
    part[w][o] = sum;
    __syncthreads();
    if (w == 0)
        gs[o] = (part[0][o] + part[1][o] + part[2][o] + part[3][o]) * (1.f / 50.f);
    __syncthreads();
    if (t < 128) {
        float z = fc1b[t];
#pragma unroll
        for (int i = 0; i < C2; ++i) z = fmaf(gs[i], fc1w[i * 128 + t], z);
        zs[t] = elu1(z);
    }
    __syncthreads();
    if (t < NCLS) {
        float l = fc2b[t];
#pragma unroll
        for (int k = 0; k < 128; ++k) l = fmaf(zs[k], fc2w[k * NCLS + t], l);
        ls[t] = l;
    }
    __syncthreads();
    if (t < NCLS) {
        float mx = ls[0];
#pragma unroll
        for (int cc = 1; cc < NCLS; ++cc) mx = fmaxf(mx, ls[cc]);
        float se = 0.f;
#pragma unroll
        for (int cc = 0; cc < NCLS; ++cc) se += expf(ls[cc] - mx);
        out[b * NCLS + t] = ls[t] - mx - logf(se);
    }
}

extern "C" void kernel_launch(void* const* d_in, const int* in_sizes, int n_in,
                              void* d_out, int out_size, void* d_ws, size_t ws_size,
                              hipStream_t stream)
{
    const float* x    = (const float*)d_in[0];
    const float* pos  = (const float*)d_in[1];
    const int*   ei   = (const int*)d_in[2];
    const float* ea   = (const float*)d_in[3];
    const int*   ei2  = (const int*)d_in[6];
    const float* n1w1 = (const float*)d_in[8];
    const float* n1b1 = (const float*)d_in[9];
    const float* n1w2 = (const float*)d_in[10];
    const float* n1b2 = (const float*)d_in[11];
    const float* root1= (const float*)d_in[12];
    const float* bias1= (const float*)d_in[13];
    const float* n2w1 = (const float*)d_in[14];
    const float* n2b1 = (const float*)d_in[15];
    const float* n2w2 = (const float*)d_in[16];
    const float* n2b2 = (const float*)d_in[17];
    const float* root2= (const float*)d_in[18];
    const float* bias2= (const float*)d_in[19];
    const float* fc1w = (const float*)d_in[20];
    const float* fc1b = (const float*)d_in[21];
    const float* fc2w = (const float*)d_in[22];
    const float* fc2b = (const float*)d_in[23];
    float* out = (float*)d_out;

    char* w = (char*)d_ws;
    unsigned short* agg1b = (unsigned short*)w;  w += (size_t)N_NODES * C1 * 2 * 2; // 2 shards
    unsigned short* x1b   = (unsigned short*)w;  w += (size_t)N1P * C1 * 2;         // 6.4 MB
    float* pos1 = (float*)w;                     w += (size_t)N1P * 2 * 4;          // 0.8 MB
    unsigned int* maxbits = (unsigned int*)w;    w += 256;
    unsigned short* agg2b = (unsigned short*)w;  w += (size_t)N1P * C2 * 2;         // 12.8 MB
    unsigned int* Bg = (unsigned int*)w;         w += 26624 * 4;
    unsigned int* W2f = (unsigned int*)w;        w += 512 * 4;

    hipMemsetAsync(agg1b, 0, (size_t)N_NODES * C1 * 2 * 2, stream);
    hipMemsetAsync(agg2b, 0, (size_t)N1P * C2 * 2, stream);
    hipMemsetAsync(maxbits, 0, 256, stream);

    bgbuild_kernel<<<106, 256, 0, stream>>>(n1w2, n1b2, n2w2, n2b2, W2f, Bg);
    conv1_kernel<<<E1 / 256, 256, 0, stream>>>(x, ea, ei, n1w1, n1b1, W2f, agg1b);
    pool1_kernel<<<(N1P * C1 + 255) / 256, 256, 0, stream>>>(agg1b, x, root1, bias1, pos, x1b, pos1);
    maxabs_kernel<<<(E2P + 255) / 256, 256, 0, stream>>>(ei2, pos1, maxbits);
    conv2_kernel<<<(E2P + 127) / 128, 256, 0, stream>>>(ei2, pos1, x1b, n2w1, n2b1, maxbits, Bg, agg2b);
    pool2_head_kernel<<<BGR, 256, 0, stream>>>(agg2b, x1b, root2, bias2,
                                               fc1w, fc1b, fc2w, fc2b, out);
}